// Round 4
// baseline (546.462 us; speedup 1.0000x reference)
//
#include <hip/hip_runtime.h>
#include <hip/hip_bf16.h>
#include <math.h>

// ---------------------------------------------------------------------------
// GATv2 x2 + Linear, fp32. CSR + fused online-softmax aggregate.
// Round 4: batch-8 online softmax in gat_agg — 8 gathers in flight, one
// transpose-butterfly multi-reduce + single exp per 8 edges, merge chain /8.
// ---------------------------------------------------------------------------

#define NEG_SLOPE 0.2f
#define CHUNK 2048

// --- edge-index dtype detection (int32 vs int64) ---------------------------
__global__ __launch_bounds__(256) void detect_kernel(const int* __restrict__ ei,
                                                     int* __restrict__ flag,
                                                     int twoE) {
    __shared__ int any;
    if (threadIdx.x == 0) any = 0;
    __syncthreads();
    int idx = 2 * (int)threadIdx.x + 1;
    if (idx < twoE && ei[idx] != 0) atomicOr(&any, 1);
    __syncthreads();
    if (threadIdx.x == 0) *flag = any;   // 1 => int32, 0 => int64
}

__global__ __launch_bounds__(256) void convert_edges(const int* __restrict__ ei,
                                                     const int* __restrict__ flag,
                                                     int* __restrict__ srcA,
                                                     int* __restrict__ dstA,
                                                     int E, int Et) {
    int e = blockIdx.x * 256 + threadIdx.x;
    if (e >= Et) return;
    int s, d;
    if (e < E) {
        if (*flag) { s = ei[e];      d = ei[E + e]; }          // int32 layout
        else       { s = ei[2 * e];  d = ei[2 * (E + e)]; }    // int64 low words
    } else {
        s = d = e - E;  // self loop
    }
    srcA[e] = s;
    dstA[e] = d;
}

// --- CSR build -------------------------------------------------------------
__global__ __launch_bounds__(256) void count_deg(const int* __restrict__ dstA,
                                                 int* __restrict__ deg, int Et) {
    int e = blockIdx.x * 256 + threadIdx.x;
    if (e < Et) atomicAdd(&deg[dstA[e]], 1);
}

__global__ __launch_bounds__(256) void scan1(const int* __restrict__ deg,
                                             int* __restrict__ rowptr,
                                             int* __restrict__ bsum, int N) {
    __shared__ int tsum[256];
    int chunk0 = blockIdx.x * CHUNK;
    int t = threadIdx.x;
    int vals[8];
    int s = 0;
    #pragma unroll
    for (int i = 0; i < 8; ++i) {
        int idx = chunk0 + t * 8 + i;
        int v = (idx < N) ? deg[idx] : 0;
        vals[i] = s;
        s += v;
    }
    tsum[t] = s;
    __syncthreads();
    for (int off = 1; off < 256; off <<= 1) {
        int v = (t >= off) ? tsum[t - off] : 0;
        __syncthreads();
        tsum[t] += v;
        __syncthreads();
    }
    int texcl = (t > 0) ? tsum[t - 1] : 0;
    #pragma unroll
    for (int i = 0; i < 8; ++i) {
        int idx = chunk0 + t * 8 + i;
        if (idx < N) rowptr[idx] = texcl + vals[i];
    }
    if (t == 255) bsum[blockIdx.x] = tsum[255];
}

__global__ void scan2(int* __restrict__ bsum, int* __restrict__ rowptr,
                      int NB, int N) {
    if (threadIdx.x == 0 && blockIdx.x == 0) {
        int s = 0;
        for (int b = 0; b < NB; ++b) { int v = bsum[b]; bsum[b] = s; s += v; }
        rowptr[N] = s;
    }
}

__global__ __launch_bounds__(256) void scan3(int* __restrict__ rowptr,
                                             const int* __restrict__ bsum,
                                             int* __restrict__ cursor, int N) {
    int idx = blockIdx.x * 256 + threadIdx.x;
    if (idx < N) {
        int v = rowptr[idx] + bsum[idx / CHUNK];
        rowptr[idx] = v;
        cursor[idx] = v;
    }
}

__global__ __launch_bounds__(256) void scatter_edges(const int* __restrict__ srcA,
                                                     const int* __restrict__ dstA,
                                                     int* __restrict__ cursor,
                                                     int* __restrict__ csr_src,
                                                     int Et) {
    int e = blockIdx.x * 256 + threadIdx.x;
    if (e < Et) {
        int pos = atomicAdd(&cursor[dstA[e]], 1);
        csr_src[pos] = srcA[e];
    }
}

// --- register-tiled GEMM: Y[N,M] = act(X[N,K] @ W[K,M] + bias) -------------
template <int M, int K, int ACT>
__global__ __launch_bounds__(256) void gemm_rt(const float* __restrict__ X,
                                               const float* __restrict__ W,
                                               const float* __restrict__ bias,
                                               float* __restrict__ Y,
                                               int N) {
    constexpr int TX   = M / 8;
    constexpr int ROWS = (256 / TX) * 8;
    constexpr int KB   = 16;
    __shared__ float Xt[KB][ROWS + 4];
    __shared__ float Wc[KB][M];

    int tid = threadIdx.x;
    int tx = tid % TX;
    int ty = tid / TX;
    int row0 = blockIdx.x * ROWS;

    float acc[8][8];
    #pragma unroll
    for (int i = 0; i < 8; ++i)
        #pragma unroll
        for (int j = 0; j < 8; ++j) acc[i][j] = 0.f;

    int lr = tid / 4;
    int kq = (tid % 4) * 4;
    constexpr int WMG = M / 4;
    int wm = (tid % WMG) * 4;
    int wk = tid / WMG;
    constexpr int WKS = 256 / WMG;

    for (int kc = 0; kc < K; kc += KB) {
        #pragma unroll
        for (int r = lr; r < ROWS; r += 64) {
            int gr = row0 + r;
            float4 xv = make_float4(0.f, 0.f, 0.f, 0.f);
            if (gr < N) xv = *(const float4*)&X[(size_t)gr * K + kc + kq];
            Xt[kq + 0][r] = xv.x;
            Xt[kq + 1][r] = xv.y;
            Xt[kq + 2][r] = xv.z;
            Xt[kq + 3][r] = xv.w;
        }
        #pragma unroll
        for (int k = wk; k < KB; k += WKS) {
            *(float4*)&Wc[k][wm] = *(const float4*)&W[(size_t)(kc + k) * M + wm];
        }
        __syncthreads();

        #pragma unroll
        for (int k = 0; k < KB; ++k) {
            float4 x0 = *(const float4*)&Xt[k][ty * 8];
            float4 x1 = *(const float4*)&Xt[k][ty * 8 + 4];
            float4 w0 = *(const float4*)&Wc[k][tx * 4];
            float4 w1 = *(const float4*)&Wc[k][tx * 4 + M / 2];
            float xs[8] = {x0.x, x0.y, x0.z, x0.w, x1.x, x1.y, x1.z, x1.w};
            float ws[8] = {w0.x, w0.y, w0.z, w0.w, w1.x, w1.y, w1.z, w1.w};
            #pragma unroll
            for (int i = 0; i < 8; ++i)
                #pragma unroll
                for (int j = 0; j < 8; ++j)
                    acc[i][j] = fmaf(xs[i], ws[j], acc[i][j]);
        }
        __syncthreads();
    }

    float4 b0 = *(const float4*)&bias[tx * 4];
    float4 b1 = *(const float4*)&bias[tx * 4 + M / 2];
    float bs[8] = {b0.x, b0.y, b0.z, b0.w, b1.x, b1.y, b1.z, b1.w};
    #pragma unroll
    for (int i = 0; i < 8; ++i) {
        int gr = row0 + ty * 8 + i;
        if (gr >= N) continue;
        float v[8];
        #pragma unroll
        for (int j = 0; j < 8; ++j) {
            float t = acc[i][j] + bs[j];
            if (ACT) t = t > 0.f ? t : expm1f(t);
            v[j] = t;
        }
        *(float4*)&Y[(size_t)gr * M + tx * 4] = make_float4(v[0], v[1], v[2], v[3]);
        *(float4*)&Y[(size_t)gr * M + tx * 4 + M / 2] = make_float4(v[4], v[5], v[6], v[7]);
    }
}

// --- fused GATv2 aggregate: batch-8 online softmax over CSR in-edges -------
// One wave per node. Lane handles CPL channels (c0 = lane*CPL); head group =
// G consecutive lanes. Per batch of 8 edges: 8 gathers in flight, per-lane
// partial logits, transpose-butterfly multi-reduce (lane l&7 ends with edge
// rev3(l&7)), single exp per lane, bpermute broadcast, one merge chain.
template <int H, int C>
__global__ __launch_bounds__(256) void gat_agg(const float* __restrict__ xl,
                                               const float* __restrict__ xr,
                                               const float* __restrict__ att,
                                               const int* __restrict__ rowptr,
                                               const int* __restrict__ csr_src,
                                               const float* __restrict__ bias,
                                               float* __restrict__ outv,
                                               int N) {
    constexpr int HC  = H * C;
    constexpr int CPL = HC / 64;   // 2 for layer1, 1 for layer2
    constexpr int G   = C / CPL;   // lanes per head group (8 or 64)
    int wave = threadIdx.x >> 6;
    int lane = threadIdx.x & 63;
    int node = blockIdx.x * 4 + wave;
    if (node >= N) return;
    int c0 = lane * CPL;

    float a0 = att[c0];
    float xr0 = xr[(size_t)node * HC + c0];
    float a1 = 0.f, xr1v = 0.f;
    if constexpr (CPL == 2) {
        a1 = att[c0 + 1];
        xr1v = xr[(size_t)node * HC + c0 + 1];
    }

    float m = -INFINITY, dsum = 0.f, acc0 = 0.f, acc1 = 0.f;
    int start = rowptr[node], end = rowptr[node + 1];

    for (int base = start; base < end; base += 64) {
        int nbatch = min(64, end - base);
        int sreg = (base + lane < end) ? csr_src[base + lane] : 0;
        for (int k0 = 0; k0 < nbatch; k0 += 8) {
            float2 xv[8];
            float part[8];
            // issue up to 8 independent gathers
            #pragma unroll
            for (int b = 0; b < 8; ++b) {
                if (k0 + b < nbatch) {
                    int s = __shfl(sreg, k0 + b, 64);
                    if constexpr (CPL == 2) {
                        xv[b] = *(const float2*)&xl[(size_t)s * HC + c0];
                    } else {
                        xv[b].x = xl[(size_t)s * HC + c0];
                        xv[b].y = 0.f;
                    }
                } else {
                    xv[b].x = 0.f; xv[b].y = 0.f;
                }
            }
            // per-lane partial logits
            #pragma unroll
            for (int b = 0; b < 8; ++b) {
                if (k0 + b < nbatch) {
                    float t0 = xv[b].x + xr0;
                    t0 = fmaxf(t0, NEG_SLOPE * t0);
                    float pt = t0 * a0;
                    if constexpr (CPL == 2) {
                        float t1 = xv[b].y + xr1v;
                        t1 = fmaxf(t1, NEG_SLOPE * t1);
                        pt = fmaf(t1, a1, pt);
                    }
                    part[b] = pt;
                } else {
                    part[b] = -INFINITY;
                }
            }
            // transpose-butterfly: 8 values -> 1 per lane (edge rev3(lane&7))
            #pragma unroll
            for (int st = 0; st < 3; ++st) {
                int o = 1 << st;
                int half = 4 >> st;
                #pragma unroll
                for (int i = 0; i < half; ++i) {
                    float keep = (lane & o) ? part[i + half] : part[i];
                    float send = (lane & o) ? part[i] : part[i + half];
                    part[i] = keep + __shfl_xor(send, o, 64);
                }
            }
            float v = part[0];
            if constexpr (G == 64) {   // complete 64-lane head sum
                v += __shfl_xor(v, 8, 64);
                v += __shfl_xor(v, 16, 64);
                v += __shfl_xor(v, 32, 64);
            }
            // batch max within 8-lane subgroup (covers all 8 edges)
            float bm = v;
            bm = fmaxf(bm, __shfl_xor(bm, 1, 64));
            bm = fmaxf(bm, __shfl_xor(bm, 2, 64));
            bm = fmaxf(bm, __shfl_xor(bm, 4, 64));
            float mnew = fmaxf(m, bm);
            float alpha = __expf(m - mnew);
            float p = __expf(v - mnew);   // one exp for this lane's edge
            // broadcast p per edge within subgroup
            float pb[8];
            int lbase = lane & ~7;
            pb[0] = __shfl(p, lbase + 0, 64);
            pb[1] = __shfl(p, lbase + 4, 64);
            pb[2] = __shfl(p, lbase + 2, 64);
            pb[3] = __shfl(p, lbase + 6, 64);
            pb[4] = __shfl(p, lbase + 1, 64);
            pb[5] = __shfl(p, lbase + 5, 64);
            pb[6] = __shfl(p, lbase + 3, 64);
            pb[7] = __shfl(p, lbase + 7, 64);
            float psum = ((pb[0] + pb[1]) + (pb[2] + pb[3])) +
                         ((pb[4] + pb[5]) + (pb[6] + pb[7]));
            float s0 = 0.f, s1 = 0.f;
            #pragma unroll
            for (int b = 0; b < 8; ++b) {
                s0 = fmaf(pb[b], xv[b].x, s0);
                if constexpr (CPL == 2) s1 = fmaf(pb[b], xv[b].y, s1);
            }
            dsum = fmaf(dsum, alpha, psum);
            acc0 = fmaf(acc0, alpha, s0);
            if constexpr (CPL == 2) acc1 = fmaf(acc1, alpha, s1);
            m = mnew;
        }
    }

    float inv = 1.f / dsum;
    float v0 = acc0 * inv + bias[c0];
    v0 = v0 > 0.f ? v0 : expm1f(v0);
    outv[(size_t)node * HC + c0] = v0;
    if constexpr (CPL == 2) {
        float v1 = acc1 * inv + bias[c0 + 1];
        v1 = v1 > 0.f ? v1 : expm1f(v1);
        outv[(size_t)node * HC + c0 + 1] = v1;
    }
}

extern "C" void kernel_launch(void* const* d_in, const int* in_sizes, int n_in,
                              void* d_out, int out_size, void* d_ws, size_t ws_size,
                              hipStream_t stream) {
    const float* x    = (const float*)d_in[0];
    const int*   ei   = (const int*)d_in[1];
    const float* Wl1  = (const float*)d_in[2];
    const float* bl1  = (const float*)d_in[3];
    const float* Wr1  = (const float*)d_in[4];
    const float* br1  = (const float*)d_in[5];
    const float* att1 = (const float*)d_in[6];
    const float* bias1= (const float*)d_in[7];
    const float* Wl2  = (const float*)d_in[8];
    const float* bl2  = (const float*)d_in[9];
    const float* Wr2  = (const float*)d_in[10];
    const float* br2  = (const float*)d_in[11];
    const float* att2 = (const float*)d_in[12];
    const float* bias2= (const float*)d_in[13];
    const float* Wlin = (const float*)d_in[14];
    const float* blin = (const float*)d_in[15];
    float* out = (float*)d_out;

    const int F = 128;
    int N  = in_sizes[0] / F;        // 50000
    int E  = in_sizes[1] / 2;        // 800000
    int Et = E + N;                  // + self loops

    // workspace layout
    float* xl1 = (float*)d_ws;            // N*128; reused: xl2, xr2 (N*64 each)
    float* xr1 = xl1 + (size_t)N * 128;   // N*128; reused: h2 (N*64)
    float* h1  = xr1 + (size_t)N * 128;   // N*128
    int* srcA   = (int*)(h1 + (size_t)N * 128);
    int* dstA   = srcA + Et;
    int* deg    = dstA + Et;              // N
    int* rowptr = deg + N;                // N+1
    int* cursor = rowptr + N + 1;         // N
    int* csr_src= cursor + N;             // Et
    int* fl     = csr_src + Et;
    int* bsum   = fl + 1;                 // <=32

    float* xl2 = xl1;
    float* xr2 = xl1 + (size_t)N * 64;
    float* h2  = xr1;

    auto cdiv = [](long a, long b) { return (int)((a + b - 1) / b); };
    int NB = cdiv(N, CHUNK);

    // edge normalization + CSR build (shared by both layers)
    detect_kernel<<<1, 256, 0, stream>>>(ei, fl, 2 * E);
    convert_edges<<<cdiv(Et, 256), 256, 0, stream>>>(ei, fl, srcA, dstA, E, Et);
    hipMemsetAsync(deg, 0, (size_t)N * 4, stream);
    count_deg<<<cdiv(Et, 256), 256, 0, stream>>>(dstA, deg, Et);
    scan1<<<NB, 256, 0, stream>>>(deg, rowptr, bsum, N);
    scan2<<<1, 64, 0, stream>>>(bsum, rowptr, NB, N);
    scan3<<<cdiv(N, 256), 256, 0, stream>>>(rowptr, bsum, cursor, N);
    scatter_edges<<<cdiv(Et, 256), 256, 0, stream>>>(srcA, dstA, cursor, csr_src, Et);

    // ---- layer 1 (H=8, C=16, concat) ----
    gemm_rt<128, 128, 0><<<cdiv(N, 128), 256, 0, stream>>>(x, Wl1, bl1, xl1, N);
    gemm_rt<128, 128, 0><<<cdiv(N, 128), 256, 0, stream>>>(x, Wr1, br1, xr1, N);
    gat_agg<8, 16><<<cdiv(N, 4), 256, 0, stream>>>(
        xl1, xr1, att1, rowptr, csr_src, bias1, h1, N);

    // ---- layer 2 (H=1, C=64) ----
    gemm_rt<64, 128, 0><<<cdiv(N, 256), 256, 0, stream>>>(h1, Wl2, bl2, xl2, N);
    gemm_rt<64, 128, 0><<<cdiv(N, 256), 256, 0, stream>>>(h1, Wr2, br2, xr2, N);
    gat_agg<1, 64><<<cdiv(N, 4), 256, 0, stream>>>(
        xl2, xr2, att2, rowptr, csr_src, bias2, h2, N);

    // ---- final linear + ELU -> d_out ----
    gemm_rt<128, 64, 1><<<cdiv(N, 128), 256, 0, stream>>>(h2, Wlin, blin, out, N);
}

// Round 5
// 467.659 us; speedup vs baseline: 1.1685x; 1.1685x over previous
//
#include <hip/hip_runtime.h>
#include <hip/hip_bf16.h>
#include <math.h>

// ---------------------------------------------------------------------------
// GATv2 x2 + Linear, fp32. CSR + fused online-softmax aggregate.
// Round 5: gat_agg reverted to R3 single-row structure (L2-friendly) +
// depth-2 prefetch; gemm_rt double-buffered staging (1 barrier/chunk,
// global loads overlapped with compute); count_deg folded into convert.
// ---------------------------------------------------------------------------

#define NEG_SLOPE 0.2f
#define CHUNK 2048

// --- edge-index dtype detection (int32 vs int64) ---------------------------
__global__ __launch_bounds__(256) void detect_kernel(const int* __restrict__ ei,
                                                     int* __restrict__ flag,
                                                     int twoE) {
    __shared__ int any;
    if (threadIdx.x == 0) any = 0;
    __syncthreads();
    int idx = 2 * (int)threadIdx.x + 1;
    if (idx < twoE && ei[idx] != 0) atomicOr(&any, 1);
    __syncthreads();
    if (threadIdx.x == 0) *flag = any;   // 1 => int32, 0 => int64
}

// convert + degree count fused (deg must be zeroed before)
__global__ __launch_bounds__(256) void convert_edges(const int* __restrict__ ei,
                                                     const int* __restrict__ flag,
                                                     int* __restrict__ srcA,
                                                     int* __restrict__ dstA,
                                                     int* __restrict__ deg,
                                                     int E, int Et) {
    int e = blockIdx.x * 256 + threadIdx.x;
    if (e >= Et) return;
    int s, d;
    if (e < E) {
        if (*flag) { s = ei[e];      d = ei[E + e]; }          // int32 layout
        else       { s = ei[2 * e];  d = ei[2 * (E + e)]; }    // int64 low words
    } else {
        s = d = e - E;  // self loop
    }
    srcA[e] = s;
    dstA[e] = d;
    atomicAdd(&deg[d], 1);
}

// --- CSR build: scan ------------------------------------------------------
__global__ __launch_bounds__(256) void scan1(const int* __restrict__ deg,
                                             int* __restrict__ rowptr,
                                             int* __restrict__ bsum, int N) {
    __shared__ int tsum[256];
    int chunk0 = blockIdx.x * CHUNK;
    int t = threadIdx.x;
    int vals[8];
    int s = 0;
    #pragma unroll
    for (int i = 0; i < 8; ++i) {
        int idx = chunk0 + t * 8 + i;
        int v = (idx < N) ? deg[idx] : 0;
        vals[i] = s;
        s += v;
    }
    tsum[t] = s;
    __syncthreads();
    for (int off = 1; off < 256; off <<= 1) {
        int v = (t >= off) ? tsum[t - off] : 0;
        __syncthreads();
        tsum[t] += v;
        __syncthreads();
    }
    int texcl = (t > 0) ? tsum[t - 1] : 0;
    #pragma unroll
    for (int i = 0; i < 8; ++i) {
        int idx = chunk0 + t * 8 + i;
        if (idx < N) rowptr[idx] = texcl + vals[i];
    }
    if (t == 255) bsum[blockIdx.x] = tsum[255];
}

__global__ void scan2(int* __restrict__ bsum, int* __restrict__ rowptr,
                      int NB, int N) {
    if (threadIdx.x == 0 && blockIdx.x == 0) {
        int s = 0;
        for (int b = 0; b < NB; ++b) { int v = bsum[b]; bsum[b] = s; s += v; }
        rowptr[N] = s;
    }
}

__global__ __launch_bounds__(256) void scan3(int* __restrict__ rowptr,
                                             const int* __restrict__ bsum,
                                             int* __restrict__ cursor, int N) {
    int idx = blockIdx.x * 256 + threadIdx.x;
    if (idx < N) {
        int v = rowptr[idx] + bsum[idx / CHUNK];
        rowptr[idx] = v;
        cursor[idx] = v;
    }
}

__global__ __launch_bounds__(256) void scatter_edges(const int* __restrict__ srcA,
                                                     const int* __restrict__ dstA,
                                                     int* __restrict__ cursor,
                                                     int* __restrict__ csr_src,
                                                     int Et) {
    int e = blockIdx.x * 256 + threadIdx.x;
    if (e < Et) {
        int pos = atomicAdd(&cursor[dstA[e]], 1);
        csr_src[pos] = srcA[e];
    }
}

// --- register-tiled GEMM, double-buffered: Y = act(X[N,K] @ W[K,M] + b) ----
// 256 threads, 8x8 acc/thread. Per chunk: ds_write staged regs -> sync ->
// issue next chunk's global loads -> compute. One barrier per chunk.
template <int M, int K, int ACT>
__global__ __launch_bounds__(256) void gemm_rt(const float* __restrict__ X,
                                               const float* __restrict__ W,
                                               const float* __restrict__ bias,
                                               float* __restrict__ Y,
                                               int N) {
    constexpr int TX   = M / 8;           // 16 (M=128) or 8 (M=64)
    constexpr int ROWS = (256 / TX) * 8;  // 128 or 256
    constexpr int KB   = 16;
    constexpr int NC   = K / KB;
    constexpr int XR   = ROWS / 64;       // float4's of X staged per thread
    constexpr int WMG  = M / 4;
    constexpr int WKS  = 256 / WMG;
    constexpr int WR   = KB / WKS;        // float4's of W staged per thread

    __shared__ float Xt[2][KB][ROWS + 4];
    __shared__ float Wc[2][KB][M];

    int tid = threadIdx.x;
    int tx = tid % TX;
    int ty = tid / TX;
    int row0 = blockIdx.x * ROWS;

    int lr = tid / 4;            // X stage: row within tile (step 64)
    int kq = (tid % 4) * 4;      // X stage: k quad
    int wm = (tid % WMG) * 4;    // W stage: col quad
    int wk = tid / WMG;          // W stage: k (step WKS)

    float4 xreg[XR];
    float4 wreg[WR];

    auto load_chunk = [&](int kc) {
        #pragma unroll
        for (int r = 0; r < XR; ++r) {
            int gr = row0 + lr + 64 * r;
            xreg[r] = (gr < N) ? *(const float4*)&X[(size_t)gr * K + kc + kq]
                               : make_float4(0.f, 0.f, 0.f, 0.f);
        }
        #pragma unroll
        for (int i = 0; i < WR; ++i)
            wreg[i] = *(const float4*)&W[(size_t)(kc + wk + WKS * i) * M + wm];
    };

    float acc[8][8];
    #pragma unroll
    for (int i = 0; i < 8; ++i)
        #pragma unroll
        for (int j = 0; j < 8; ++j) acc[i][j] = 0.f;

    load_chunk(0);
    for (int ci = 0; ci < NC; ++ci) {
        int buf = ci & 1;
        #pragma unroll
        for (int r = 0; r < XR; ++r) {
            Xt[buf][kq + 0][lr + 64 * r] = xreg[r].x;
            Xt[buf][kq + 1][lr + 64 * r] = xreg[r].y;
            Xt[buf][kq + 2][lr + 64 * r] = xreg[r].z;
            Xt[buf][kq + 3][lr + 64 * r] = xreg[r].w;
        }
        #pragma unroll
        for (int i = 0; i < WR; ++i)
            *(float4*)&Wc[buf][wk + WKS * i][wm] = wreg[i];
        __syncthreads();
        if (ci + 1 < NC) load_chunk((ci + 1) * KB);

        #pragma unroll
        for (int k = 0; k < KB; ++k) {
            float4 x0 = *(const float4*)&Xt[buf][k][ty * 8];
            float4 x1 = *(const float4*)&Xt[buf][k][ty * 8 + 4];
            float4 w0 = *(const float4*)&Wc[buf][k][tx * 4];
            float4 w1 = *(const float4*)&Wc[buf][k][tx * 4 + M / 2];
            float xs[8] = {x0.x, x0.y, x0.z, x0.w, x1.x, x1.y, x1.z, x1.w};
            float ws[8] = {w0.x, w0.y, w0.z, w0.w, w1.x, w1.y, w1.z, w1.w};
            #pragma unroll
            for (int i = 0; i < 8; ++i)
                #pragma unroll
                for (int j = 0; j < 8; ++j)
                    acc[i][j] = fmaf(xs[i], ws[j], acc[i][j]);
        }
        __syncthreads();
    }

    float4 b0 = *(const float4*)&bias[tx * 4];
    float4 b1 = *(const float4*)&bias[tx * 4 + M / 2];
    float bs[8] = {b0.x, b0.y, b0.z, b0.w, b1.x, b1.y, b1.z, b1.w};
    #pragma unroll
    for (int i = 0; i < 8; ++i) {
        int gr = row0 + ty * 8 + i;
        if (gr >= N) continue;
        float v[8];
        #pragma unroll
        for (int j = 0; j < 8; ++j) {
            float t = acc[i][j] + bs[j];
            if (ACT) t = t > 0.f ? t : expm1f(t);
            v[j] = t;
        }
        *(float4*)&Y[(size_t)gr * M + tx * 4] = make_float4(v[0], v[1], v[2], v[3]);
        *(float4*)&Y[(size_t)gr * M + tx * 4 + M / 2] = make_float4(v[4], v[5], v[6], v[7]);
    }
}

// --- fused GATv2 aggregate: online softmax over CSR in-edges ---------------
// R3 structure (one row in flight-window, L2-friendly) + depth-2 prefetch.
template <int H, int C>
__global__ __launch_bounds__(256) void gat_agg(const float* __restrict__ xl,
                                               const float* __restrict__ xr,
                                               const float* __restrict__ att,
                                               const int* __restrict__ rowptr,
                                               const int* __restrict__ csr_src,
                                               const float* __restrict__ bias,
                                               float* __restrict__ outv,
                                               int N) {
    constexpr int HC  = H * C;
    constexpr int CPL = HC / 64;   // 2 for layer1, 1 for layer2
    constexpr int G   = C / CPL;   // lanes per head group (8 or 64)
    int wave = threadIdx.x >> 6;
    int lane = threadIdx.x & 63;
    int node = blockIdx.x * 4 + wave;
    if (node >= N) return;
    int c0 = lane * CPL;

    float a0 = att[c0];
    float xr0 = xr[(size_t)node * HC + c0];
    float a1 = 0.f, xr1v = 0.f;
    if constexpr (CPL == 2) {
        a1 = att[c0 + 1];
        xr1v = xr[(size_t)node * HC + c0 + 1];
    }

    float m = -INFINITY, dsum = 0.f, acc0 = 0.f, acc1 = 0.f;
    int start = rowptr[node], end = rowptr[node + 1];

    auto loadrow = [&](int s) -> float2 {
        if constexpr (CPL == 2) {
            return *(const float2*)&xl[(size_t)s * HC + c0];
        } else {
            float2 r; r.x = xl[(size_t)s * HC + c0]; r.y = 0.f;
            return r;
        }
    };

    for (int base = start; base < end; base += 64) {
        int nbatch = min(64, end - base);
        int sreg = (base + lane < end) ? csr_src[base + lane] : 0;
        float2 xnext = loadrow(__shfl(sreg, 0, 64));
        for (int k = 0; k < nbatch; ++k) {
            float2 xcur = xnext;
            if (k + 1 < nbatch)
                xnext = loadrow(__shfl(sreg, k + 1, 64));
            float t0 = xcur.x + xr0;
            t0 = fmaxf(t0, NEG_SLOPE * t0);
            float part = t0 * a0;
            if constexpr (CPL == 2) {
                float t1 = xcur.y + xr1v;
                t1 = fmaxf(t1, NEG_SLOPE * t1);
                part = fmaf(t1, a1, part);
            }
            #pragma unroll
            for (int off = 1; off < G; off <<= 1)
                part += __shfl_xor(part, off, 64);
            float mnew = fmaxf(m, part);
            float alpha = __expf(m - mnew);
            float p = __expf(part - mnew);
            dsum = fmaf(dsum, alpha, p);
            acc0 = fmaf(acc0, alpha, p * xcur.x);
            if constexpr (CPL == 2) acc1 = fmaf(acc1, alpha, p * xcur.y);
            m = mnew;
        }
    }

    float inv = 1.f / dsum;
    float v0 = acc0 * inv + bias[c0];
    v0 = v0 > 0.f ? v0 : expm1f(v0);
    outv[(size_t)node * HC + c0] = v0;
    if constexpr (CPL == 2) {
        float v1 = acc1 * inv + bias[c0 + 1];
        v1 = v1 > 0.f ? v1 : expm1f(v1);
        outv[(size_t)node * HC + c0 + 1] = v1;
    }
}

extern "C" void kernel_launch(void* const* d_in, const int* in_sizes, int n_in,
                              void* d_out, int out_size, void* d_ws, size_t ws_size,
                              hipStream_t stream) {
    const float* x    = (const float*)d_in[0];
    const int*   ei   = (const int*)d_in[1];
    const float* Wl1  = (const float*)d_in[2];
    const float* bl1  = (const float*)d_in[3];
    const float* Wr1  = (const float*)d_in[4];
    const float* br1  = (const float*)d_in[5];
    const float* att1 = (const float*)d_in[6];
    const float* bias1= (const float*)d_in[7];
    const float* Wl2  = (const float*)d_in[8];
    const float* bl2  = (const float*)d_in[9];
    const float* Wr2  = (const float*)d_in[10];
    const float* br2  = (const float*)d_in[11];
    const float* att2 = (const float*)d_in[12];
    const float* bias2= (const float*)d_in[13];
    const float* Wlin = (const float*)d_in[14];
    const float* blin = (const float*)d_in[15];
    float* out = (float*)d_out;

    const int F = 128;
    int N  = in_sizes[0] / F;        // 50000
    int E  = in_sizes[1] / 2;        // 800000
    int Et = E + N;                  // + self loops

    // workspace layout
    float* xl1 = (float*)d_ws;            // N*128; reused: xl2, xr2 (N*64 each)
    float* xr1 = xl1 + (size_t)N * 128;   // N*128; reused: h2 (N*64)
    float* h1  = xr1 + (size_t)N * 128;   // N*128
    int* srcA   = (int*)(h1 + (size_t)N * 128);
    int* dstA   = srcA + Et;
    int* deg    = dstA + Et;              // N
    int* rowptr = deg + N;                // N+1
    int* cursor = rowptr + N + 1;         // N
    int* csr_src= cursor + N;             // Et
    int* fl     = csr_src + Et;
    int* bsum   = fl + 1;                 // <=32

    float* xl2 = xl1;
    float* xr2 = xl1 + (size_t)N * 64;
    float* h2  = xr1;

    auto cdiv = [](long a, long b) { return (int)((a + b - 1) / b); };
    int NB = cdiv(N, CHUNK);

    // edge normalization + CSR build (shared by both layers)
    detect_kernel<<<1, 256, 0, stream>>>(ei, fl, 2 * E);
    hipMemsetAsync(deg, 0, (size_t)N * 4, stream);
    convert_edges<<<cdiv(Et, 256), 256, 0, stream>>>(ei, fl, srcA, dstA, deg, E, Et);
    scan1<<<NB, 256, 0, stream>>>(deg, rowptr, bsum, N);
    scan2<<<1, 64, 0, stream>>>(bsum, rowptr, NB, N);
    scan3<<<cdiv(N, 256), 256, 0, stream>>>(rowptr, bsum, cursor, N);
    scatter_edges<<<cdiv(Et, 256), 256, 0, stream>>>(srcA, dstA, cursor, csr_src, Et);

    // ---- layer 1 (H=8, C=16, concat) ----
    gemm_rt<128, 128, 0><<<cdiv(N, 128), 256, 0, stream>>>(x, Wl1, bl1, xl1, N);
    gemm_rt<128, 128, 0><<<cdiv(N, 128), 256, 0, stream>>>(x, Wr1, br1, xr1, N);
    gat_agg<8, 16><<<cdiv(N, 4), 256, 0, stream>>>(
        xl1, xr1, att1, rowptr, csr_src, bias1, h1, N);

    // ---- layer 2 (H=1, C=64) ----
    gemm_rt<64, 128, 0><<<cdiv(N, 256), 256, 0, stream>>>(h1, Wl2, bl2, xl2, N);
    gemm_rt<64, 128, 0><<<cdiv(N, 256), 256, 0, stream>>>(h1, Wr2, br2, xr2, N);
    gat_agg<1, 64><<<cdiv(N, 4), 256, 0, stream>>>(
        xl2, xr2, att2, rowptr, csr_src, bias2, h2, N);

    // ---- final linear + ELU -> d_out ----
    gemm_rt<128, 64, 1><<<cdiv(N, 128), 256, 0, stream>>>(h2, Wlin, blin, out, N);
}

// Round 6
// 444.990 us; speedup vs baseline: 1.2280x; 1.0509x over previous
//
#include <hip/hip_runtime.h>
#include <hip/hip_bf16.h>
#include <math.h>

// ---------------------------------------------------------------------------
// GATv2 x2 + Linear, fp32. CSR + fused online-softmax aggregate.
// Round 6: batch-2 online softmax in gat_agg (merge chain per 2 edges,
// 2-value transpose butterfly, 1 exp/lane covers both edges, pair-ahead
// prefetch = 4 rows in flight — R4's batch-8 blew L2 at 8 rows).
// ---------------------------------------------------------------------------

#define NEG_SLOPE 0.2f
#define CHUNK 2048

// --- edge-index dtype detection (int32 vs int64) ---------------------------
__global__ __launch_bounds__(256) void detect_kernel(const int* __restrict__ ei,
                                                     int* __restrict__ flag,
                                                     int twoE) {
    __shared__ int any;
    if (threadIdx.x == 0) any = 0;
    __syncthreads();
    int idx = 2 * (int)threadIdx.x + 1;
    if (idx < twoE && ei[idx] != 0) atomicOr(&any, 1);
    __syncthreads();
    if (threadIdx.x == 0) *flag = any;   // 1 => int32, 0 => int64
}

// convert + degree count fused (deg must be zeroed before)
__global__ __launch_bounds__(256) void convert_edges(const int* __restrict__ ei,
                                                     const int* __restrict__ flag,
                                                     int* __restrict__ srcA,
                                                     int* __restrict__ dstA,
                                                     int* __restrict__ deg,
                                                     int E, int Et) {
    int e = blockIdx.x * 256 + threadIdx.x;
    if (e >= Et) return;
    int s, d;
    if (e < E) {
        if (*flag) { s = ei[e];      d = ei[E + e]; }          // int32 layout
        else       { s = ei[2 * e];  d = ei[2 * (E + e)]; }    // int64 low words
    } else {
        s = d = e - E;  // self loop
    }
    srcA[e] = s;
    dstA[e] = d;
    atomicAdd(&deg[d], 1);
}

// --- CSR build: scan ------------------------------------------------------
__global__ __launch_bounds__(256) void scan1(const int* __restrict__ deg,
                                             int* __restrict__ rowptr,
                                             int* __restrict__ bsum, int N) {
    __shared__ int tsum[256];
    int chunk0 = blockIdx.x * CHUNK;
    int t = threadIdx.x;
    int vals[8];
    int s = 0;
    #pragma unroll
    for (int i = 0; i < 8; ++i) {
        int idx = chunk0 + t * 8 + i;
        int v = (idx < N) ? deg[idx] : 0;
        vals[i] = s;
        s += v;
    }
    tsum[t] = s;
    __syncthreads();
    for (int off = 1; off < 256; off <<= 1) {
        int v = (t >= off) ? tsum[t - off] : 0;
        __syncthreads();
        tsum[t] += v;
        __syncthreads();
    }
    int texcl = (t > 0) ? tsum[t - 1] : 0;
    #pragma unroll
    for (int i = 0; i < 8; ++i) {
        int idx = chunk0 + t * 8 + i;
        if (idx < N) rowptr[idx] = texcl + vals[i];
    }
    if (t == 255) bsum[blockIdx.x] = tsum[255];
}

__global__ void scan2(int* __restrict__ bsum, int* __restrict__ rowptr,
                      int NB, int N) {
    if (threadIdx.x == 0 && blockIdx.x == 0) {
        int s = 0;
        for (int b = 0; b < NB; ++b) { int v = bsum[b]; bsum[b] = s; s += v; }
        rowptr[N] = s;
    }
}

__global__ __launch_bounds__(256) void scan3(int* __restrict__ rowptr,
                                             const int* __restrict__ bsum,
                                             int* __restrict__ cursor, int N) {
    int idx = blockIdx.x * 256 + threadIdx.x;
    if (idx < N) {
        int v = rowptr[idx] + bsum[idx / CHUNK];
        rowptr[idx] = v;
        cursor[idx] = v;
    }
}

__global__ __launch_bounds__(256) void scatter_edges(const int* __restrict__ srcA,
                                                     const int* __restrict__ dstA,
                                                     int* __restrict__ cursor,
                                                     int* __restrict__ csr_src,
                                                     int Et) {
    int e = blockIdx.x * 256 + threadIdx.x;
    if (e < Et) {
        int pos = atomicAdd(&cursor[dstA[e]], 1);
        csr_src[pos] = srcA[e];
    }
}

// --- register-tiled GEMM, double-buffered: Y = act(X[N,K] @ W[K,M] + b) ----
template <int M, int K, int ACT>
__global__ __launch_bounds__(256) void gemm_rt(const float* __restrict__ X,
                                               const float* __restrict__ W,
                                               const float* __restrict__ bias,
                                               float* __restrict__ Y,
                                               int N) {
    constexpr int TX   = M / 8;           // 16 (M=128) or 8 (M=64)
    constexpr int ROWS = (256 / TX) * 8;  // 128 or 256
    constexpr int KB   = 16;
    constexpr int NC   = K / KB;
    constexpr int XR   = ROWS / 64;
    constexpr int WMG  = M / 4;
    constexpr int WKS  = 256 / WMG;
    constexpr int WR   = KB / WKS;

    __shared__ float Xt[2][KB][ROWS + 4];
    __shared__ float Wc[2][KB][M];

    int tid = threadIdx.x;
    int tx = tid % TX;
    int ty = tid / TX;
    int row0 = blockIdx.x * ROWS;

    int lr = tid / 4;
    int kq = (tid % 4) * 4;
    int wm = (tid % WMG) * 4;
    int wk = tid / WMG;

    float4 xreg[XR];
    float4 wreg[WR];

    auto load_chunk = [&](int kc) {
        #pragma unroll
        for (int r = 0; r < XR; ++r) {
            int gr = row0 + lr + 64 * r;
            xreg[r] = (gr < N) ? *(const float4*)&X[(size_t)gr * K + kc + kq]
                               : make_float4(0.f, 0.f, 0.f, 0.f);
        }
        #pragma unroll
        for (int i = 0; i < WR; ++i)
            wreg[i] = *(const float4*)&W[(size_t)(kc + wk + WKS * i) * M + wm];
    };

    float acc[8][8];
    #pragma unroll
    for (int i = 0; i < 8; ++i)
        #pragma unroll
        for (int j = 0; j < 8; ++j) acc[i][j] = 0.f;

    load_chunk(0);
    for (int ci = 0; ci < NC; ++ci) {
        int buf = ci & 1;
        #pragma unroll
        for (int r = 0; r < XR; ++r) {
            Xt[buf][kq + 0][lr + 64 * r] = xreg[r].x;
            Xt[buf][kq + 1][lr + 64 * r] = xreg[r].y;
            Xt[buf][kq + 2][lr + 64 * r] = xreg[r].z;
            Xt[buf][kq + 3][lr + 64 * r] = xreg[r].w;
        }
        #pragma unroll
        for (int i = 0; i < WR; ++i)
            *(float4*)&Wc[buf][wk + WKS * i][wm] = wreg[i];
        __syncthreads();
        if (ci + 1 < NC) load_chunk((ci + 1) * KB);

        #pragma unroll
        for (int k = 0; k < KB; ++k) {
            float4 x0 = *(const float4*)&Xt[buf][k][ty * 8];
            float4 x1 = *(const float4*)&Xt[buf][k][ty * 8 + 4];
            float4 w0 = *(const float4*)&Wc[buf][k][tx * 4];
            float4 w1 = *(const float4*)&Wc[buf][k][tx * 4 + M / 2];
            float xs[8] = {x0.x, x0.y, x0.z, x0.w, x1.x, x1.y, x1.z, x1.w};
            float ws[8] = {w0.x, w0.y, w0.z, w0.w, w1.x, w1.y, w1.z, w1.w};
            #pragma unroll
            for (int i = 0; i < 8; ++i)
                #pragma unroll
                for (int j = 0; j < 8; ++j)
                    acc[i][j] = fmaf(xs[i], ws[j], acc[i][j]);
        }
        __syncthreads();
    }

    float4 b0 = *(const float4*)&bias[tx * 4];
    float4 b1 = *(const float4*)&bias[tx * 4 + M / 2];
    float bs[8] = {b0.x, b0.y, b0.z, b0.w, b1.x, b1.y, b1.z, b1.w};
    #pragma unroll
    for (int i = 0; i < 8; ++i) {
        int gr = row0 + ty * 8 + i;
        if (gr >= N) continue;
        float v[8];
        #pragma unroll
        for (int j = 0; j < 8; ++j) {
            float t = acc[i][j] + bs[j];
            if (ACT) t = t > 0.f ? t : expm1f(t);
            v[j] = t;
        }
        *(float4*)&Y[(size_t)gr * M + tx * 4] = make_float4(v[0], v[1], v[2], v[3]);
        *(float4*)&Y[(size_t)gr * M + tx * 4 + M / 2] = make_float4(v[4], v[5], v[6], v[7]);
    }
}

// --- fused GATv2 aggregate: batch-2 online softmax over CSR in-edges -------
// One wave per node; lane owns CPL channels (c0=lane*CPL), head = G lanes.
// Per pair of edges: 2 gathers in flight (+2 prefetched), partial logits,
// select+xor1 butterfly (even lanes own edge k, odd own k+1; parity preserved
// by all later xor stages), xor2..xor(G/2) complete the head sum, single exp
// per lane, one merge-rescale per pair.
template <int H, int C>
__global__ __launch_bounds__(256) void gat_agg(const float* __restrict__ xl,
                                               const float* __restrict__ xr,
                                               const float* __restrict__ att,
                                               const int* __restrict__ rowptr,
                                               const int* __restrict__ csr_src,
                                               const float* __restrict__ bias,
                                               float* __restrict__ outv,
                                               int N) {
    constexpr int HC  = H * C;
    constexpr int CPL = HC / 64;   // 2 for layer1, 1 for layer2
    constexpr int G   = C / CPL;   // lanes per head group (8 or 64)
    int wave = threadIdx.x >> 6;
    int lane = threadIdx.x & 63;
    int node = blockIdx.x * 4 + wave;
    if (node >= N) return;
    int c0 = lane * CPL;

    float a0 = att[c0];
    float xr0 = xr[(size_t)node * HC + c0];
    float a1 = 0.f, xr1v = 0.f;
    if constexpr (CPL == 2) {
        a1 = att[c0 + 1];
        xr1v = xr[(size_t)node * HC + c0 + 1];
    }

    float m = -INFINITY, dsum = 0.f, acc0 = 0.f, acc1 = 0.f;
    int start = rowptr[node], end = rowptr[node + 1];

    auto loadrow = [&](int s) -> float2 {
        if constexpr (CPL == 2) {
            return *(const float2*)&xl[(size_t)s * HC + c0];
        } else {
            float2 r; r.x = xl[(size_t)s * HC + c0]; r.y = 0.f;
            return r;
        }
    };

    auto logit_part = [&](const float2& xv) -> float {
        float t0 = xv.x + xr0;
        t0 = fmaxf(t0, NEG_SLOPE * t0);
        float pt = t0 * a0;
        if constexpr (CPL == 2) {
            float t1 = xv.y + xr1v;
            t1 = fmaxf(t1, NEG_SLOPE * t1);
            pt = fmaf(t1, a1, pt);
        }
        return pt;
    };

    for (int base = start; base < end; base += 64) {
        int nbatch = min(64, end - base);
        int sreg = (base + lane < end) ? csr_src[base + lane] : 0;
        float2 xa = loadrow(__shfl(sreg, 0, 64));
        float2 xb = (1 < nbatch) ? loadrow(__shfl(sreg, 1, 64))
                                 : make_float2(0.f, 0.f);
        for (int k0 = 0; k0 < nbatch; k0 += 2) {
            float2 ca = xa, cb = xb;
            bool vb = (k0 + 1 < nbatch);
            if (k0 + 2 < nbatch) {
                xa = loadrow(__shfl(sreg, k0 + 2, 64));
                xb = (k0 + 3 < nbatch) ? loadrow(__shfl(sreg, k0 + 3, 64))
                                       : make_float2(0.f, 0.f);
            }
            float pa  = logit_part(ca);
            float pb_ = vb ? logit_part(cb) : -INFINITY;
            // butterfly stage 1 with select: even lanes -> edge a, odd -> b
            float keep = (lane & 1) ? pb_ : pa;
            float send = (lane & 1) ? pa : pb_;
            float part = keep + __shfl_xor(send, 1, 64);
            #pragma unroll
            for (int off = 2; off < G; off <<= 1)
                part += __shfl_xor(part, off, 64);
            // part = full logit of edge (k0 + (lane&1))
            float bm = fmaxf(part, __shfl_xor(part, 1, 64));
            float mnew = fmaxf(m, bm);
            float alpha = __expf(m - mnew);
            float p = __expf(part - mnew);   // one exp: this lane's edge
            float po = __shfl_xor(p, 1, 64);
            float p0 = (lane & 1) ? po : p;
            float p1 = (lane & 1) ? p : po;
            dsum = fmaf(dsum, alpha, p0 + p1);
            acc0 = fmaf(acc0, alpha, fmaf(p0, ca.x, p1 * cb.x));
            if constexpr (CPL == 2)
                acc1 = fmaf(acc1, alpha, fmaf(p0, ca.y, p1 * cb.y));
            m = mnew;
        }
    }

    float inv = 1.f / dsum;
    float v0 = acc0 * inv + bias[c0];
    v0 = v0 > 0.f ? v0 : expm1f(v0);
    outv[(size_t)node * HC + c0] = v0;
    if constexpr (CPL == 2) {
        float v1 = acc1 * inv + bias[c0 + 1];
        v1 = v1 > 0.f ? v1 : expm1f(v1);
        outv[(size_t)node * HC + c0 + 1] = v1;
    }
}

extern "C" void kernel_launch(void* const* d_in, const int* in_sizes, int n_in,
                              void* d_out, int out_size, void* d_ws, size_t ws_size,
                              hipStream_t stream) {
    const float* x    = (const float*)d_in[0];
    const int*   ei   = (const int*)d_in[1];
    const float* Wl1  = (const float*)d_in[2];
    const float* bl1  = (const float*)d_in[3];
    const float* Wr1  = (const float*)d_in[4];
    const float* br1  = (const float*)d_in[5];
    const float* att1 = (const float*)d_in[6];
    const float* bias1= (const float*)d_in[7];
    const float* Wl2  = (const float*)d_in[8];
    const float* bl2  = (const float*)d_in[9];
    const float* Wr2  = (const float*)d_in[10];
    const float* br2  = (const float*)d_in[11];
    const float* att2 = (const float*)d_in[12];
    const float* bias2= (const float*)d_in[13];
    const float* Wlin = (const float*)d_in[14];
    const float* blin = (const float*)d_in[15];
    float* out = (float*)d_out;

    const int F = 128;
    int N  = in_sizes[0] / F;        // 50000
    int E  = in_sizes[1] / 2;        // 800000
    int Et = E + N;                  // + self loops

    // workspace layout
    float* xl1 = (float*)d_ws;            // N*128; reused: xl2, xr2 (N*64 each)
    float* xr1 = xl1 + (size_t)N * 128;   // N*128; reused: h2 (N*64)
    float* h1  = xr1 + (size_t)N * 128;   // N*128
    int* srcA   = (int*)(h1 + (size_t)N * 128);
    int* dstA   = srcA + Et;
    int* deg    = dstA + Et;              // N
    int* rowptr = deg + N;                // N+1
    int* cursor = rowptr + N + 1;         // N
    int* csr_src= cursor + N;             // Et
    int* fl     = csr_src + Et;
    int* bsum   = fl + 1;                 // <=32

    float* xl2 = xl1;
    float* xr2 = xl1 + (size_t)N * 64;
    float* h2  = xr1;

    auto cdiv = [](long a, long b) { return (int)((a + b - 1) / b); };
    int NB = cdiv(N, CHUNK);

    // edge normalization + CSR build (shared by both layers)
    detect_kernel<<<1, 256, 0, stream>>>(ei, fl, 2 * E);
    hipMemsetAsync(deg, 0, (size_t)N * 4, stream);
    convert_edges<<<cdiv(Et, 256), 256, 0, stream>>>(ei, fl, srcA, dstA, deg, E, Et);
    scan1<<<NB, 256, 0, stream>>>(deg, rowptr, bsum, N);
    scan2<<<1, 64, 0, stream>>>(bsum, rowptr, NB, N);
    scan3<<<cdiv(N, 256), 256, 0, stream>>>(rowptr, bsum, cursor, N);
    scatter_edges<<<cdiv(Et, 256), 256, 0, stream>>>(srcA, dstA, cursor, csr_src, Et);

    // ---- layer 1 (H=8, C=16, concat) ----
    gemm_rt<128, 128, 0><<<cdiv(N, 128), 256, 0, stream>>>(x, Wl1, bl1, xl1, N);
    gemm_rt<128, 128, 0><<<cdiv(N, 128), 256, 0, stream>>>(x, Wr1, br1, xr1, N);
    gat_agg<8, 16><<<cdiv(N, 4), 256, 0, stream>>>(
        xl1, xr1, att1, rowptr, csr_src, bias1, h1, N);

    // ---- layer 2 (H=1, C=64) ----
    gemm_rt<64, 128, 0><<<cdiv(N, 256), 256, 0, stream>>>(h1, Wl2, bl2, xl2, N);
    gemm_rt<64, 128, 0><<<cdiv(N, 256), 256, 0, stream>>>(h1, Wr2, br2, xr2, N);
    gat_agg<1, 64><<<cdiv(N, 4), 256, 0, stream>>>(
        xl2, xr2, att2, rowptr, csr_src, bias2, h2, N);

    // ---- final linear + ELU -> d_out ----
    gemm_rt<128, 64, 1><<<cdiv(N, 128), 256, 0, stream>>>(h2, Wlin, blin, out, N);
}

// Round 7
// 412.280 us; speedup vs baseline: 1.3255x; 1.0793x over previous
//
#include <hip/hip_runtime.h>
#include <hip/hip_bf16.h>
#include <math.h>

// ---------------------------------------------------------------------------
// GATv2 x2 + Linear. CSR + batch-2 online-softmax aggregate (fp32) +
// Round 7: bf16 MFMA GEMMs (fp32 accumulate, RNE cast fused into LDS
// staging). Fragment layouts per m89-verified 16x16x32 bf16 mapping.
// ---------------------------------------------------------------------------

#define NEG_SLOPE 0.2f
#define CHUNK 2048

typedef __attribute__((ext_vector_type(8))) short short8;
typedef __attribute__((ext_vector_type(4))) float f32x4;

__device__ __forceinline__ unsigned short f2bf(float f) {
    unsigned u = __float_as_uint(f);
    u += 0x7FFF + ((u >> 16) & 1);   // RNE
    return (unsigned short)(u >> 16);
}
__device__ __forceinline__ unsigned pack2(float a, float b) {
    return (unsigned)f2bf(a) | ((unsigned)f2bf(b) << 16);
}

// --- edge-index dtype detection (int32 vs int64) ---------------------------
__global__ __launch_bounds__(256) void detect_kernel(const int* __restrict__ ei,
                                                     int* __restrict__ flag,
                                                     int twoE) {
    __shared__ int any;
    if (threadIdx.x == 0) any = 0;
    __syncthreads();
    int idx = 2 * (int)threadIdx.x + 1;
    if (idx < twoE && ei[idx] != 0) atomicOr(&any, 1);
    __syncthreads();
    if (threadIdx.x == 0) *flag = any;   // 1 => int32, 0 => int64
}

// convert + degree count fused (deg must be zeroed before)
__global__ __launch_bounds__(256) void convert_edges(const int* __restrict__ ei,
                                                     const int* __restrict__ flag,
                                                     int* __restrict__ srcA,
                                                     int* __restrict__ dstA,
                                                     int* __restrict__ deg,
                                                     int E, int Et) {
    int e = blockIdx.x * 256 + threadIdx.x;
    if (e >= Et) return;
    int s, d;
    if (e < E) {
        if (*flag) { s = ei[e];      d = ei[E + e]; }          // int32 layout
        else       { s = ei[2 * e];  d = ei[2 * (E + e)]; }    // int64 low words
    } else {
        s = d = e - E;  // self loop
    }
    srcA[e] = s;
    dstA[e] = d;
    atomicAdd(&deg[d], 1);
}

// --- CSR build: scan ------------------------------------------------------
__global__ __launch_bounds__(256) void scan1(const int* __restrict__ deg,
                                             int* __restrict__ rowptr,
                                             int* __restrict__ bsum, int N) {
    __shared__ int tsum[256];
    int chunk0 = blockIdx.x * CHUNK;
    int t = threadIdx.x;
    int vals[8];
    int s = 0;
    #pragma unroll
    for (int i = 0; i < 8; ++i) {
        int idx = chunk0 + t * 8 + i;
        int v = (idx < N) ? deg[idx] : 0;
        vals[i] = s;
        s += v;
    }
    tsum[t] = s;
    __syncthreads();
    for (int off = 1; off < 256; off <<= 1) {
        int v = (t >= off) ? tsum[t - off] : 0;
        __syncthreads();
        tsum[t] += v;
        __syncthreads();
    }
    int texcl = (t > 0) ? tsum[t - 1] : 0;
    #pragma unroll
    for (int i = 0; i < 8; ++i) {
        int idx = chunk0 + t * 8 + i;
        if (idx < N) rowptr[idx] = texcl + vals[i];
    }
    if (t == 255) bsum[blockIdx.x] = tsum[255];
}

__global__ void scan2(int* __restrict__ bsum, int* __restrict__ rowptr,
                      int NB, int N) {
    if (threadIdx.x == 0 && blockIdx.x == 0) {
        int s = 0;
        for (int b = 0; b < NB; ++b) { int v = bsum[b]; bsum[b] = s; s += v; }
        rowptr[N] = s;
    }
}

__global__ __launch_bounds__(256) void scan3(int* __restrict__ rowptr,
                                             const int* __restrict__ bsum,
                                             int* __restrict__ cursor, int N) {
    int idx = blockIdx.x * 256 + threadIdx.x;
    if (idx < N) {
        int v = rowptr[idx] + bsum[idx / CHUNK];
        rowptr[idx] = v;
        cursor[idx] = v;
    }
}

__global__ __launch_bounds__(256) void scatter_edges(const int* __restrict__ srcA,
                                                     const int* __restrict__ dstA,
                                                     int* __restrict__ cursor,
                                                     int* __restrict__ csr_src,
                                                     int Et) {
    int e = blockIdx.x * 256 + threadIdx.x;
    if (e < Et) {
        int pos = atomicAdd(&cursor[dstA[e]], 1);
        csr_src[pos] = srcA[e];
    }
}

// --- bf16 MFMA GEMM: Y[N,M] = act(X[N,K] @ W[K,M] + bias), fp32 in/out -----
// 256 threads = 4 waves; block tile 128 rows x M cols. W staged transposed
// (Wt[col][k], +8 pad) as bf16 once; X streamed in 64-k chunks via LDS
// (cast fused into staging). Wave w: rows w*32..w*32+31 (2 row-tiles), all
// M/16 col-tiles. 16x16x32 bf16 MFMA, fp32 acc.
// Layouts (m89-verified): A[m=lane&15][k=(lane>>4)*8+j]; B sym; D row=
// (lane>>4)*4+reg, col=lane&15.
template <int M, int K, int ACT>
__global__ __launch_bounds__(256) void gemm_mfma(const float* __restrict__ X,
                                                 const float* __restrict__ W,
                                                 const float* __restrict__ bias,
                                                 float* __restrict__ Y,
                                                 int N) {
    constexpr int KPW  = K + 8;   // Wt padded stride (shorts) — 16B-multiple
    constexpr int XP   = 72;      // Xb chunk stride (64+8 shorts)
    constexpr int COLT = M / 16;
    constexpr int NCH  = K / 64;

    __shared__ short Wt[M * KPW];
    __shared__ short Xb[128 * XP];

    int tid = threadIdx.x;
    int wave = tid >> 6, lane = tid & 63;
    int row0 = blockIdx.x * 128;
    int mrow = lane & 15;
    int kq8 = (lane >> 4) * 8;

    // stage W transposed (coalesced global reads, scalar LDS writes; one-time)
    for (int idx = tid; idx < K * M; idx += 256) {
        int k = idx / M, c = idx - k * M;
        Wt[c * KPW + k] = (short)f2bf(W[idx]);
    }

    f32x4 acc[2][COLT];
    #pragma unroll
    for (int tm = 0; tm < 2; ++tm)
        #pragma unroll
        for (int tn = 0; tn < COLT; ++tn)
            acc[tm][tn] = (f32x4){0.f, 0.f, 0.f, 0.f};

    for (int ch = 0; ch < NCH; ++ch) {
        __syncthreads();   // covers Wt stage (ch=0) / prev-chunk readers
        // stage X chunk: 128 rows x 64 k, fp32->bf16
        for (int idx = tid; idx < 128 * 16; idx += 256) {
            int r = idx >> 4, kq = (idx & 15) << 2;
            int gr = row0 + r;
            float4 xv = make_float4(0.f, 0.f, 0.f, 0.f);
            if (gr < N) xv = *(const float4*)&X[(size_t)gr * K + ch * 64 + kq];
            uint2 pk;
            pk.x = pack2(xv.x, xv.y);
            pk.y = pack2(xv.z, xv.w);
            *(uint2*)&Xb[r * XP + kq] = pk;
        }
        __syncthreads();

        #pragma unroll
        for (int ks = 0; ks < 2; ++ks) {
            short8 a[2], b[COLT];
            #pragma unroll
            for (int tm = 0; tm < 2; ++tm)
                a[tm] = *(const short8*)&Xb[(wave * 32 + tm * 16 + mrow) * XP +
                                            ks * 32 + kq8];
            #pragma unroll
            for (int tn = 0; tn < COLT; ++tn)
                b[tn] = *(const short8*)&Wt[(tn * 16 + mrow) * KPW +
                                            ch * 64 + ks * 32 + kq8];
            #pragma unroll
            for (int tm = 0; tm < 2; ++tm)
                #pragma unroll
                for (int tn = 0; tn < COLT; ++tn)
                    acc[tm][tn] = __builtin_amdgcn_mfma_f32_16x16x32_bf16(
                        a[tm], b[tn], acc[tm][tn], 0, 0, 0);
        }
    }

    int q = lane >> 4;
    #pragma unroll
    for (int tn = 0; tn < COLT; ++tn) {
        int col = tn * 16 + mrow;
        float bc = bias[col];
        #pragma unroll
        for (int tm = 0; tm < 2; ++tm) {
            int base = row0 + wave * 32 + tm * 16 + q * 4;
            #pragma unroll
            for (int r = 0; r < 4; ++r) {
                int gr = base + r;
                if (gr < N) {
                    float v = acc[tm][tn][r] + bc;
                    if (ACT) v = v > 0.f ? v : expm1f(v);
                    Y[(size_t)gr * M + col] = v;
                }
            }
        }
    }
}

// --- fused GATv2 aggregate: batch-2 online softmax over CSR in-edges -------
template <int H, int C>
__global__ __launch_bounds__(256) void gat_agg(const float* __restrict__ xl,
                                               const float* __restrict__ xr,
                                               const float* __restrict__ att,
                                               const int* __restrict__ rowptr,
                                               const int* __restrict__ csr_src,
                                               const float* __restrict__ bias,
                                               float* __restrict__ outv,
                                               int N) {
    constexpr int HC  = H * C;
    constexpr int CPL = HC / 64;   // 2 for layer1, 1 for layer2
    constexpr int G   = C / CPL;   // lanes per head group (8 or 64)
    int wave = threadIdx.x >> 6;
    int lane = threadIdx.x & 63;
    int node = blockIdx.x * 4 + wave;
    if (node >= N) return;
    int c0 = lane * CPL;

    float a0 = att[c0];
    float xr0 = xr[(size_t)node * HC + c0];
    float a1 = 0.f, xr1v = 0.f;
    if constexpr (CPL == 2) {
        a1 = att[c0 + 1];
        xr1v = xr[(size_t)node * HC + c0 + 1];
    }

    float m = -INFINITY, dsum = 0.f, acc0 = 0.f, acc1 = 0.f;
    int start = rowptr[node], end = rowptr[node + 1];

    auto loadrow = [&](int s) -> float2 {
        if constexpr (CPL == 2) {
            return *(const float2*)&xl[(size_t)s * HC + c0];
        } else {
            float2 r; r.x = xl[(size_t)s * HC + c0]; r.y = 0.f;
            return r;
        }
    };

    auto logit_part = [&](const float2& xv) -> float {
        float t0 = xv.x + xr0;
        t0 = fmaxf(t0, NEG_SLOPE * t0);
        float pt = t0 * a0;
        if constexpr (CPL == 2) {
            float t1 = xv.y + xr1v;
            t1 = fmaxf(t1, NEG_SLOPE * t1);
            pt = fmaf(t1, a1, pt);
        }
        return pt;
    };

    for (int base = start; base < end; base += 64) {
        int nbatch = min(64, end - base);
        int sreg = (base + lane < end) ? csr_src[base + lane] : 0;
        float2 xa = loadrow(__shfl(sreg, 0, 64));
        float2 xb = (1 < nbatch) ? loadrow(__shfl(sreg, 1, 64))
                                 : make_float2(0.f, 0.f);
        for (int k0 = 0; k0 < nbatch; k0 += 2) {
            float2 ca = xa, cb = xb;
            bool vb = (k0 + 1 < nbatch);
            if (k0 + 2 < nbatch) {
                xa = loadrow(__shfl(sreg, k0 + 2, 64));
                xb = (k0 + 3 < nbatch) ? loadrow(__shfl(sreg, k0 + 3, 64))
                                       : make_float2(0.f, 0.f);
            }
            float pa  = logit_part(ca);
            float pb_ = vb ? logit_part(cb) : -INFINITY;
            float keep = (lane & 1) ? pb_ : pa;
            float send = (lane & 1) ? pa : pb_;
            float part = keep + __shfl_xor(send, 1, 64);
            #pragma unroll
            for (int off = 2; off < G; off <<= 1)
                part += __shfl_xor(part, off, 64);
            float bm = fmaxf(part, __shfl_xor(part, 1, 64));
            float mnew = fmaxf(m, bm);
            float alpha = __expf(m - mnew);
            float p = __expf(part - mnew);
            float po = __shfl_xor(p, 1, 64);
            float p0 = (lane & 1) ? po : p;
            float p1 = (lane & 1) ? p : po;
            dsum = fmaf(dsum, alpha, p0 + p1);
            acc0 = fmaf(acc0, alpha, fmaf(p0, ca.x, p1 * cb.x));
            if constexpr (CPL == 2)
                acc1 = fmaf(acc1, alpha, fmaf(p0, ca.y, p1 * cb.y));
            m = mnew;
        }
    }

    float inv = 1.f / dsum;
    float v0 = acc0 * inv + bias[c0];
    v0 = v0 > 0.f ? v0 : expm1f(v0);
    outv[(size_t)node * HC + c0] = v0;
    if constexpr (CPL == 2) {
        float v1 = acc1 * inv + bias[c0 + 1];
        v1 = v1 > 0.f ? v1 : expm1f(v1);
        outv[(size_t)node * HC + c0 + 1] = v1;
    }
}

extern "C" void kernel_launch(void* const* d_in, const int* in_sizes, int n_in,
                              void* d_out, int out_size, void* d_ws, size_t ws_size,
                              hipStream_t stream) {
    const float* x    = (const float*)d_in[0];
    const int*   ei   = (const int*)d_in[1];
    const float* Wl1  = (const float*)d_in[2];
    const float* bl1  = (const float*)d_in[3];
    const float* Wr1  = (const float*)d_in[4];
    const float* br1  = (const float*)d_in[5];
    const float* att1 = (const float*)d_in[6];
    const float* bias1= (const float*)d_in[7];
    const float* Wl2  = (const float*)d_in[8];
    const float* bl2  = (const float*)d_in[9];
    const float* Wr2  = (const float*)d_in[10];
    const float* br2  = (const float*)d_in[11];
    const float* att2 = (const float*)d_in[12];
    const float* bias2= (const float*)d_in[13];
    const float* Wlin = (const float*)d_in[14];
    const float* blin = (const float*)d_in[15];
    float* out = (float*)d_out;

    const int F = 128;
    int N  = in_sizes[0] / F;        // 50000
    int E  = in_sizes[1] / 2;        // 800000
    int Et = E + N;                  // + self loops

    // workspace layout
    float* xl1 = (float*)d_ws;            // N*128; reused: xl2, xr2 (N*64 each)
    float* xr1 = xl1 + (size_t)N * 128;   // N*128; reused: h2 (N*64)
    float* h1  = xr1 + (size_t)N * 128;   // N*128
    int* srcA   = (int*)(h1 + (size_t)N * 128);
    int* dstA   = srcA + Et;
    int* deg    = dstA + Et;              // N
    int* rowptr = deg + N;                // N+1
    int* cursor = rowptr + N + 1;         // N
    int* csr_src= cursor + N;             // Et
    int* fl     = csr_src + Et;
    int* bsum   = fl + 1;                 // <=32

    float* xl2 = xl1;
    float* xr2 = xl1 + (size_t)N * 64;
    float* h2  = xr1;

    auto cdiv = [](long a, long b) { return (int)((a + b - 1) / b); };
    int NB = cdiv(N, CHUNK);

    // edge normalization + CSR build (shared by both layers)
    detect_kernel<<<1, 256, 0, stream>>>(ei, fl, 2 * E);
    hipMemsetAsync(deg, 0, (size_t)N * 4, stream);
    convert_edges<<<cdiv(Et, 256), 256, 0, stream>>>(ei, fl, srcA, dstA, deg, E, Et);
    scan1<<<NB, 256, 0, stream>>>(deg, rowptr, bsum, N);
    scan2<<<1, 64, 0, stream>>>(bsum, rowptr, NB, N);
    scan3<<<cdiv(N, 256), 256, 0, stream>>>(rowptr, bsum, cursor, N);
    scatter_edges<<<cdiv(Et, 256), 256, 0, stream>>>(srcA, dstA, cursor, csr_src, Et);

    // ---- layer 1 (H=8, C=16, concat) ----
    gemm_mfma<128, 128, 0><<<cdiv(N, 128), 256, 0, stream>>>(x, Wl1, bl1, xl1, N);
    gemm_mfma<128, 128, 0><<<cdiv(N, 128), 256, 0, stream>>>(x, Wr1, br1, xr1, N);
    gat_agg<8, 16><<<cdiv(N, 4), 256, 0, stream>>>(
        xl1, xr1, att1, rowptr, csr_src, bias1, h1, N);

    // ---- layer 2 (H=1, C=64) ----
    gemm_mfma<64, 128, 0><<<cdiv(N, 128), 256, 0, stream>>>(h1, Wl2, bl2, xl2, N);
    gemm_mfma<64, 128, 0><<<cdiv(N, 128), 256, 0, stream>>>(h1, Wr2, br2, xr2, N);
    gat_agg<1, 64><<<cdiv(N, 4), 256, 0, stream>>>(
        xl2, xr2, att2, rowptr, csr_src, bias2, h2, N);

    // ---- final linear + ELU -> d_out ----
    gemm_mfma<128, 64, 1><<<cdiv(N, 128), 256, 0, stream>>>(h2, Wlin, blin, out, N);
}

// Round 8
// 386.911 us; speedup vs baseline: 1.4124x; 1.0656x over previous
//
#include <hip/hip_runtime.h>
#include <hip/hip_bf16.h>
#include <math.h>

// ---------------------------------------------------------------------------
// GATv2 x2 + Linear. CSR + batch-2 online-softmax aggregate + bf16 MFMA GEMM.
// Round 8: bf16 intermediates (xl1/xr1/h1/h2 stored bf16 — halves the
// scattered gather traffic and GEMM epilogue/input traffic) + weights
// pre-transposed to bf16 once by prep_w (GEMM stages W via uint4 copies,
// no per-block transpose).
// ---------------------------------------------------------------------------

#define NEG_SLOPE 0.2f
#define CHUNK 2048

typedef __attribute__((ext_vector_type(8))) short short8;
typedef __attribute__((ext_vector_type(4))) float f32x4;

__device__ __forceinline__ unsigned short f2bf(float f) {
    unsigned u = __float_as_uint(f);
    u += 0x7FFF + ((u >> 16) & 1);   // RNE
    return (unsigned short)(u >> 16);
}
__device__ __forceinline__ unsigned pack2(float a, float b) {
    return (unsigned)f2bf(a) | ((unsigned)f2bf(b) << 16);
}

// --- edge-index dtype detection (int32 vs int64) ---------------------------
__global__ __launch_bounds__(256) void detect_kernel(const int* __restrict__ ei,
                                                     int* __restrict__ flag,
                                                     int twoE) {
    __shared__ int any;
    if (threadIdx.x == 0) any = 0;
    __syncthreads();
    int idx = 2 * (int)threadIdx.x + 1;
    if (idx < twoE && ei[idx] != 0) atomicOr(&any, 1);
    __syncthreads();
    if (threadIdx.x == 0) *flag = any;   // 1 => int32, 0 => int64
}

// convert + degree count fused (deg must be zeroed before)
__global__ __launch_bounds__(256) void convert_edges(const int* __restrict__ ei,
                                                     const int* __restrict__ flag,
                                                     int* __restrict__ srcA,
                                                     int* __restrict__ dstA,
                                                     int* __restrict__ deg,
                                                     int E, int Et) {
    int e = blockIdx.x * 256 + threadIdx.x;
    if (e >= Et) return;
    int s, d;
    if (e < E) {
        if (*flag) { s = ei[e];      d = ei[E + e]; }          // int32 layout
        else       { s = ei[2 * e];  d = ei[2 * (E + e)]; }    // int64 low words
    } else {
        s = d = e - E;  // self loop
    }
    srcA[e] = s;
    dstA[e] = d;
    atomicAdd(&deg[d], 1);
}

// --- CSR build: scan ------------------------------------------------------
__global__ __launch_bounds__(256) void scan1(const int* __restrict__ deg,
                                             int* __restrict__ rowptr,
                                             int* __restrict__ bsum, int N) {
    __shared__ int tsum[256];
    int chunk0 = blockIdx.x * CHUNK;
    int t = threadIdx.x;
    int vals[8];
    int s = 0;
    #pragma unroll
    for (int i = 0; i < 8; ++i) {
        int idx = chunk0 + t * 8 + i;
        int v = (idx < N) ? deg[idx] : 0;
        vals[i] = s;
        s += v;
    }
    tsum[t] = s;
    __syncthreads();
    for (int off = 1; off < 256; off <<= 1) {
        int v = (t >= off) ? tsum[t - off] : 0;
        __syncthreads();
        tsum[t] += v;
        __syncthreads();
    }
    int texcl = (t > 0) ? tsum[t - 1] : 0;
    #pragma unroll
    for (int i = 0; i < 8; ++i) {
        int idx = chunk0 + t * 8 + i;
        if (idx < N) rowptr[idx] = texcl + vals[i];
    }
    if (t == 255) bsum[blockIdx.x] = tsum[255];
}

__global__ void scan2(int* __restrict__ bsum, int* __restrict__ rowptr,
                      int NB, int N) {
    if (threadIdx.x == 0 && blockIdx.x == 0) {
        int s = 0;
        for (int b = 0; b < NB; ++b) { int v = bsum[b]; bsum[b] = s; s += v; }
        rowptr[N] = s;
    }
}

__global__ __launch_bounds__(256) void scan3(int* __restrict__ rowptr,
                                             const int* __restrict__ bsum,
                                             int* __restrict__ cursor, int N) {
    int idx = blockIdx.x * 256 + threadIdx.x;
    if (idx < N) {
        int v = rowptr[idx] + bsum[idx / CHUNK];
        rowptr[idx] = v;
        cursor[idx] = v;
    }
}

__global__ __launch_bounds__(256) void scatter_edges(const int* __restrict__ srcA,
                                                     const int* __restrict__ dstA,
                                                     int* __restrict__ cursor,
                                                     int* __restrict__ csr_src,
                                                     int Et) {
    int e = blockIdx.x * 256 + threadIdx.x;
    if (e < Et) {
        int pos = atomicAdd(&cursor[dstA[e]], 1);
        csr_src[pos] = srcA[e];
    }
}

// --- weight prep: fp32 [K][M] -> bf16 transposed [M][K+8] ------------------
// Offsets (shorts): l1=0, r1=17408, l2=34816, r2=43520, lin=52224 (tot 61440)
__global__ __launch_bounds__(256) void prep_w(const float* __restrict__ Wl1,
                                              const float* __restrict__ Wr1,
                                              const float* __restrict__ Wl2,
                                              const float* __restrict__ Wr2,
                                              const float* __restrict__ Wlin,
                                              unsigned short* __restrict__ Wt) {
    int idx = blockIdx.x * 256 + threadIdx.x;
    if (idx < 16384) {
        int k = idx >> 7, c = idx & 127;
        Wt[c * 136 + k] = f2bf(Wl1[idx]);
    } else if (idx < 32768) {
        int j = idx - 16384; int k = j >> 7, c = j & 127;
        Wt[17408 + c * 136 + k] = f2bf(Wr1[j]);
    } else if (idx < 40960) {
        int j = idx - 32768; int k = j >> 6, c = j & 63;
        Wt[34816 + c * 136 + k] = f2bf(Wl2[j]);
    } else if (idx < 49152) {
        int j = idx - 40960; int k = j >> 6, c = j & 63;
        Wt[43520 + c * 136 + k] = f2bf(Wr2[j]);
    } else if (idx < 57344) {
        int j = idx - 49152; int k = j >> 7, c = j & 127;
        Wt[52224 + c * 72 + k] = f2bf(Wlin[j]);
    }
}

// --- bf16 MFMA GEMM: Y[N,M] = act(X[N,K] @ W + bias) -----------------------
// X fp32 (INBF=0) or bf16 (INBF=1); Y fp32 (OUTBF=0) or bf16-packed (OUTBF=1).
// W pre-transposed bf16 [M][K+8] in global, staged to LDS via uint4 copies.
// 256 thr = 4 waves; tile 128 rows x M. 16x16x32 bf16 MFMA (m89 layouts).
template <int M, int K, int ACT, int INBF, int OUTBF>
__global__ __launch_bounds__(256) void gemm_mfma(const void* __restrict__ Xv,
                                                 const unsigned short* __restrict__ Wtg,
                                                 const float* __restrict__ bias,
                                                 void* __restrict__ Yv,
                                                 int N) {
    constexpr int KPW  = K + 8;
    constexpr int XP   = 72;
    constexpr int COLT = M / 16;
    constexpr int NCH  = K / 64;

    __shared__ short Wt[M * KPW];
    __shared__ short Xb[128 * XP];

    int tid = threadIdx.x;
    int wave = tid >> 6, lane = tid & 63;
    int row0 = blockIdx.x * 128;
    int mrow = lane & 15;
    int kq8 = (lane >> 4) * 8;

    // stage pre-transposed W: flat vector copy
    for (int i = tid; i < M * KPW / 8; i += 256)
        ((uint4*)Wt)[i] = ((const uint4*)Wtg)[i];

    f32x4 acc[2][COLT];
    #pragma unroll
    for (int tm = 0; tm < 2; ++tm)
        #pragma unroll
        for (int tn = 0; tn < COLT; ++tn)
            acc[tm][tn] = (f32x4){0.f, 0.f, 0.f, 0.f};

    for (int ch = 0; ch < NCH; ++ch) {
        __syncthreads();   // covers Wt stage (ch=0) / prev-chunk readers
        if (INBF) {
            const unsigned short* X = (const unsigned short*)Xv;
            for (int idx = tid; idx < 128 * 8; idx += 256) {
                int r = idx >> 3, g = (idx & 7) * 8;
                int gr = row0 + r;
                short8 v = {0, 0, 0, 0, 0, 0, 0, 0};
                if (gr < N) v = *(const short8*)&X[(size_t)gr * K + ch * 64 + g];
                *(short8*)&Xb[r * XP + g] = v;
            }
        } else {
            const float* X = (const float*)Xv;
            for (int idx = tid; idx < 128 * 16; idx += 256) {
                int r = idx >> 4, kq = (idx & 15) << 2;
                int gr = row0 + r;
                float4 xv = make_float4(0.f, 0.f, 0.f, 0.f);
                if (gr < N) xv = *(const float4*)&X[(size_t)gr * K + ch * 64 + kq];
                uint2 pk;
                pk.x = pack2(xv.x, xv.y);
                pk.y = pack2(xv.z, xv.w);
                *(uint2*)&Xb[r * XP + kq] = pk;
            }
        }
        __syncthreads();

        #pragma unroll
        for (int ks = 0; ks < 2; ++ks) {
            short8 a[2], b[COLT];
            #pragma unroll
            for (int tm = 0; tm < 2; ++tm)
                a[tm] = *(const short8*)&Xb[(wave * 32 + tm * 16 + mrow) * XP +
                                            ks * 32 + kq8];
            #pragma unroll
            for (int tn = 0; tn < COLT; ++tn)
                b[tn] = *(const short8*)&Wt[(tn * 16 + mrow) * KPW +
                                            ch * 64 + ks * 32 + kq8];
            #pragma unroll
            for (int tm = 0; tm < 2; ++tm)
                #pragma unroll
                for (int tn = 0; tn < COLT; ++tn)
                    acc[tm][tn] = __builtin_amdgcn_mfma_f32_16x16x32_bf16(
                        a[tm], b[tn], acc[tm][tn], 0, 0, 0);
        }
    }

    int q = lane >> 4;
    #pragma unroll
    for (int tn = 0; tn < COLT; ++tn) {
        int col = tn * 16 + mrow;
        float bc = bias[col];
        #pragma unroll
        for (int tm = 0; tm < 2; ++tm) {
            int base = row0 + wave * 32 + tm * 16 + q * 4;
            #pragma unroll
            for (int r = 0; r < 4; ++r) {
                int gr = base + r;
                float v = acc[tm][tn][r] + bc;
                if (ACT) v = v > 0.f ? v : expm1f(v);
                if (OUTBF) {
                    float other = __shfl_xor(v, 1, 64);  // col^1 partner
                    if (!(mrow & 1) && gr < N)
                        ((unsigned*)Yv)[(size_t)gr * (M / 2) + (col >> 1)] =
                            pack2(v, other);
                } else {
                    if (gr < N) ((float*)Yv)[(size_t)gr * M + col] = v;
                }
            }
        }
    }
}

// --- fused GATv2 aggregate: batch-2 online softmax over CSR in-edges -------
// INBF: xl/xr stored bf16-packed (CPL==2 only: one dword = lane's 2 channels)
// OUTBF: output stored bf16-packed.
template <int H, int C, int INBF, int OUTBF>
__global__ __launch_bounds__(256) void gat_agg(const void* __restrict__ xl,
                                               const void* __restrict__ xr,
                                               const float* __restrict__ att,
                                               const int* __restrict__ rowptr,
                                               const int* __restrict__ csr_src,
                                               const float* __restrict__ bias,
                                               void* __restrict__ outv,
                                               int N) {
    constexpr int HC  = H * C;
    constexpr int CPL = HC / 64;   // 2 for layer1, 1 for layer2
    constexpr int G   = C / CPL;   // lanes per head group (8 or 64)
    int wave = threadIdx.x >> 6;
    int lane = threadIdx.x & 63;
    int node = blockIdx.x * 4 + wave;
    if (node >= N) return;
    int c0 = lane * CPL;

    float a0 = att[c0];
    float a1 = 0.f, xr0, xr1v = 0.f;
    if constexpr (INBF) {
        unsigned u = ((const unsigned*)xr)[(size_t)node * (HC / 2) + lane];
        xr0 = __uint_as_float(u << 16);
        xr1v = __uint_as_float(u & 0xffff0000u);
        a1 = att[c0 + 1];
    } else {
        xr0 = ((const float*)xr)[(size_t)node * HC + c0];
        if constexpr (CPL == 2) {
            a1 = att[c0 + 1];
            xr1v = ((const float*)xr)[(size_t)node * HC + c0 + 1];
        }
    }

    float m = -INFINITY, dsum = 0.f, acc0 = 0.f, acc1 = 0.f;
    int start = rowptr[node], end = rowptr[node + 1];

    auto loadrow = [&](int s) -> float2 {
        float2 r;
        if constexpr (INBF) {
            unsigned u = ((const unsigned*)xl)[(size_t)s * (HC / 2) + lane];
            r.x = __uint_as_float(u << 16);
            r.y = __uint_as_float(u & 0xffff0000u);
        } else if constexpr (CPL == 2) {
            r = *(const float2*)&((const float*)xl)[(size_t)s * HC + c0];
        } else {
            r.x = ((const float*)xl)[(size_t)s * HC + c0];
            r.y = 0.f;
        }
        return r;
    };

    auto logit_part = [&](const float2& xv) -> float {
        float t0 = xv.x + xr0;
        t0 = fmaxf(t0, NEG_SLOPE * t0);
        float pt = t0 * a0;
        if constexpr (CPL == 2) {
            float t1 = xv.y + xr1v;
            t1 = fmaxf(t1, NEG_SLOPE * t1);
            pt = fmaf(t1, a1, pt);
        }
        return pt;
    };

    for (int base = start; base < end; base += 64) {
        int nbatch = min(64, end - base);
        int sreg = (base + lane < end) ? csr_src[base + lane] : 0;
        float2 xa = loadrow(__shfl(sreg, 0, 64));
        float2 xb = (1 < nbatch) ? loadrow(__shfl(sreg, 1, 64))
                                 : make_float2(0.f, 0.f);
        for (int k0 = 0; k0 < nbatch; k0 += 2) {
            float2 ca = xa, cb = xb;
            bool vb = (k0 + 1 < nbatch);
            if (k0 + 2 < nbatch) {
                xa = loadrow(__shfl(sreg, k0 + 2, 64));
                xb = (k0 + 3 < nbatch) ? loadrow(__shfl(sreg, k0 + 3, 64))
                                       : make_float2(0.f, 0.f);
            }
            float pa  = logit_part(ca);
            float pb_ = vb ? logit_part(cb) : -INFINITY;
            float keep = (lane & 1) ? pb_ : pa;
            float send = (lane & 1) ? pa : pb_;
            float part = keep + __shfl_xor(send, 1, 64);
            #pragma unroll
            for (int off = 2; off < G; off <<= 1)
                part += __shfl_xor(part, off, 64);
            float bm = fmaxf(part, __shfl_xor(part, 1, 64));
            float mnew = fmaxf(m, bm);
            float alpha = __expf(m - mnew);
            float p = __expf(part - mnew);
            float po = __shfl_xor(p, 1, 64);
            float p0 = (lane & 1) ? po : p;
            float p1 = (lane & 1) ? p : po;
            dsum = fmaf(dsum, alpha, p0 + p1);
            acc0 = fmaf(acc0, alpha, fmaf(p0, ca.x, p1 * cb.x));
            if constexpr (CPL == 2)
                acc1 = fmaf(acc1, alpha, fmaf(p0, ca.y, p1 * cb.y));
            m = mnew;
        }
    }

    float inv = 1.f / dsum;
    float v0 = acc0 * inv + bias[c0];
    v0 = v0 > 0.f ? v0 : expm1f(v0);
    if constexpr (CPL == 2) {
        float v1 = acc1 * inv + bias[c0 + 1];
        v1 = v1 > 0.f ? v1 : expm1f(v1);
        if constexpr (OUTBF) {
            ((unsigned*)outv)[(size_t)node * (HC / 2) + lane] = pack2(v0, v1);
        } else {
            ((float*)outv)[(size_t)node * HC + c0] = v0;
            ((float*)outv)[(size_t)node * HC + c0 + 1] = v1;
        }
    } else {
        if constexpr (OUTBF) {
            float po = __shfl_xor(v0, 1, 64);
            if (!(lane & 1))
                ((unsigned*)outv)[(size_t)node * (HC / 2) + (lane >> 1)] =
                    pack2(v0, po);
        } else {
            ((float*)outv)[(size_t)node * HC + c0] = v0;
        }
    }
}

extern "C" void kernel_launch(void* const* d_in, const int* in_sizes, int n_in,
                              void* d_out, int out_size, void* d_ws, size_t ws_size,
                              hipStream_t stream) {
    const float* x    = (const float*)d_in[0];
    const int*   ei   = (const int*)d_in[1];
    const float* Wl1  = (const float*)d_in[2];
    const float* bl1  = (const float*)d_in[3];
    const float* Wr1  = (const float*)d_in[4];
    const float* br1  = (const float*)d_in[5];
    const float* att1 = (const float*)d_in[6];
    const float* bias1= (const float*)d_in[7];
    const float* Wl2  = (const float*)d_in[8];
    const float* bl2  = (const float*)d_in[9];
    const float* Wr2  = (const float*)d_in[10];
    const float* br2  = (const float*)d_in[11];
    const float* att2 = (const float*)d_in[12];
    const float* bias2= (const float*)d_in[13];
    const float* Wlin = (const float*)d_in[14];
    const float* blin = (const float*)d_in[15];
    float* out = (float*)d_out;

    const int F = 128;
    int N  = in_sizes[0] / F;        // 50000
    int E  = in_sizes[1] / 2;        // 800000
    int Et = E + N;                  // + self loops

    // workspace layout (Wt first for 16B alignment of uint4 copies)
    unsigned short* Wt = (unsigned short*)d_ws;   // 61440 shorts (122880 B)
    unsigned* xl1u = (unsigned*)(Wt + 61440);     // N*64 (bf16 pairs)
    unsigned* xr1u = xl1u + (size_t)N * 64;       // N*64
    unsigned* h1u  = xr1u + (size_t)N * 64;       // N*64
    float* xl2 = (float*)(h1u + (size_t)N * 64);  // N*64 fp32
    float* xr2 = xl2 + (size_t)N * 64;            // N*64 fp32
    unsigned* h2u = (unsigned*)(xr2 + (size_t)N * 64);  // N*32 (bf16 pairs)
    int* srcA   = (int*)(h2u + (size_t)N * 32);
    int* dstA   = srcA + Et;
    int* deg    = dstA + Et;              // N
    int* rowptr = deg + N;                // N+1
    int* cursor = rowptr + N + 1;         // N
    int* csr_src= cursor + N;             // Et
    int* fl     = csr_src + Et;
    int* bsum   = fl + 1;                 // <=32

    auto cdiv = [](long a, long b) { return (int)((a + b - 1) / b); };
    int NB = cdiv(N, CHUNK);

    // weight prep + edge normalization + CSR build
    prep_w<<<224, 256, 0, stream>>>(Wl1, Wr1, Wl2, Wr2, Wlin, Wt);
    detect_kernel<<<1, 256, 0, stream>>>(ei, fl, 2 * E);
    hipMemsetAsync(deg, 0, (size_t)N * 4, stream);
    convert_edges<<<cdiv(Et, 256), 256, 0, stream>>>(ei, fl, srcA, dstA, deg, E, Et);
    scan1<<<NB, 256, 0, stream>>>(deg, rowptr, bsum, N);
    scan2<<<1, 64, 0, stream>>>(bsum, rowptr, NB, N);
    scan3<<<cdiv(N, 256), 256, 0, stream>>>(rowptr, bsum, cursor, N);
    scatter_edges<<<cdiv(Et, 256), 256, 0, stream>>>(srcA, dstA, cursor, csr_src, Et);

    // ---- layer 1 (H=8, C=16, concat): fp32 x -> bf16 xl1/xr1 ----
    gemm_mfma<128, 128, 0, 0, 1><<<cdiv(N, 128), 256, 0, stream>>>(
        x, Wt, bl1, xl1u, N);
    gemm_mfma<128, 128, 0, 0, 1><<<cdiv(N, 128), 256, 0, stream>>>(
        x, Wt + 17408, br1, xr1u, N);
    gat_agg<8, 16, 1, 1><<<cdiv(N, 4), 256, 0, stream>>>(
        xl1u, xr1u, att1, rowptr, csr_src, bias1, h1u, N);

    // ---- layer 2 (H=1, C=64): bf16 h1 -> fp32 xl2/xr2 ----
    gemm_mfma<64, 128, 0, 1, 0><<<cdiv(N, 128), 256, 0, stream>>>(
        h1u, Wt + 34816, bl2, xl2, N);
    gemm_mfma<64, 128, 0, 1, 0><<<cdiv(N, 128), 256, 0, stream>>>(
        h1u, Wt + 43520, br2, xr2, N);
    gat_agg<1, 64, 0, 1><<<cdiv(N, 4), 256, 0, stream>>>(
        xl2, xr2, att2, rowptr, csr_src, bias2, h2u, N);

    // ---- final linear + ELU: bf16 h2 -> fp32 d_out ----
    gemm_mfma<128, 64, 1, 1, 0><<<cdiv(N, 128), 256, 0, stream>>>(
        h2u, Wt + 52224, blin, out, N);
}